// Round 9
// baseline (210.407 us; speedup 1.0000x reference)
//
#include <hip/hip_runtime.h>
#include <hip/hip_fp16.h>

#define NN 4096
constexpr int TPB = 256;
constexpr int TILE = 128;            // 128x128 tiles
constexpr int NT = NN / TILE;        // 32 tiles per dim
constexpr int NBLK = NT * NT;        // 1024 blocks (4/CU co-resident)
constexpr int NPART = NT;            // 32 partial slots per axis

typedef float    f32x4 __attribute__((ext_vector_type(4)));
typedef _Float16 f16x8 __attribute__((ext_vector_type(8)));

__device__ __forceinline__ float sigmoidf_(float x) {
    return 1.0f / (1.0f + __expf(-x));
}

// STEPK: 1 = first step (sigma^1 from bs, prev := 0)
//        2 = second step (cur from partials, prev = sigma^1 from bs)
//        3 = generic (cur from rpC/cpC, prev from rpP/cpP)
// SRC: 0 = read base_f (f32 interleaved), 1 = read fp16 df
// WDF: write fp16 df (step 1).  EPI: fused out_f epilogue (step 5, SRC=0).
template <int STEPK, int SRC, int WDF, int EPI>
__global__ __launch_bounds__(TPB) void pass_kernel(
    const float2* __restrict__ bs, const f32x4* __restrict__ bf,
    f16x8* __restrict__ df, f32x4* __restrict__ of,
    const float* __restrict__ rpC, const float* __restrict__ cpC,
    const float* __restrict__ rpP, const float* __restrict__ cpP,
    float* __restrict__ rpO, float* __restrict__ cpO,
    const float* __restrict__ wptr) {
    const int t = threadIdx.x;
    const int ct = blockIdx.x & (NT - 1);   // col tile
    const int rt = blockIdx.x >> 5;         // row tile
    const int j0 = ct * TILE;
    const int i0 = rt * TILE;
    const float w = wptr[0];

    __shared__ float sc_row[TILE];   // sigma_cur at rows
    __shared__ float sp_row[TILE];   // sigma_prev at rows
    __shared__ float s0c_col[TILE];  // 1 - sigma_cur at cols
    __shared__ float wp_col[TILE];   // w * (1 - sigma_prev) at cols
    __shared__ float colred[4][TILE];

    // ---- prologue: redundant sigma recompute for this block's 256 indices ----
    {
        const bool isRow = (t < TILE);
        const int x = isRow ? (i0 + t) : (j0 + (t - TILE));
        float scur, sprev;
        float2 b = bs[x];
        if (STEPK == 1) {
            scur = sigmoidf_(b.y - b.x);
            sprev = 0.0f;
        } else {
            float m0 = 0.f, m1 = 0.f;
#pragma unroll
            for (int s = 0; s < NPART; ++s) {
                m0 += rpC[(size_t)s * NN + x];
                m1 += cpC[(size_t)s * NN + x];
            }
            scur = sigmoidf_((b.y + w * m1) - (b.x + w * m0));
            if (STEPK == 2) {
                sprev = sigmoidf_(b.y - b.x);
            } else {
                float p0 = 0.f, p1 = 0.f;
#pragma unroll
                for (int s = 0; s < NPART; ++s) {
                    p0 += rpP[(size_t)s * NN + x];
                    p1 += cpP[(size_t)s * NN + x];
                }
                sprev = sigmoidf_((b.y + w * p1) - (b.x + w * p0));
            }
        }
        if (isRow) {
            sc_row[t] = scur;
            sp_row[t] = sprev;
        } else {
            s0c_col[t - TILE] = 1.0f - scur;
            wp_col[t - TILE] = w * (1.0f - sprev);
        }
    }
    __syncthreads();

    // ---- main loop: thread (c, rg) owns cols jg..jg+7, rows i0+rg*8..+7 ----
    const int c = t & 15;
    const int rg = t >> 4;
    const int jg = j0 + c * 8;

    float s0cv[8], ws0p[8];
#pragma unroll
    for (int k = 0; k < 8; ++k) {
        s0cv[k] = s0c_col[c * 8 + k];
        ws0p[k] = wp_col[c * 8 + k];
    }
    float colacc[8] = {0.f, 0.f, 0.f, 0.f, 0.f, 0.f, 0.f, 0.f};

#pragma unroll 2
    for (int rr = 0; rr < 8; ++rr) {
        const int lr = rg * 8 + rr;
        const int i = i0 + lr;
        const float s1ci = sc_row[lr];
        const float s1pi = sp_row[lr];
        float dd[8];
        if (SRC == 1) {
            f16x8 h = df[((size_t)i * NN + jg) >> 3];
#pragma unroll
            for (int k = 0; k < 8; ++k) dd[k] = (float)h[k];
        } else {
            const size_t u = ((size_t)i * NN + jg) >> 1;  // f32x4 index
            f32x4 v0 = bf[u], v1 = bf[u + 1], v2 = bf[u + 2], v3 = bf[u + 3];
            dd[0] = v0.y - v0.x; dd[1] = v0.w - v0.z;
            dd[2] = v1.y - v1.x; dd[3] = v1.w - v1.z;
            dd[4] = v2.y - v2.x; dd[5] = v2.w - v2.z;
            dd[6] = v3.y - v3.x; dd[7] = v3.w - v3.z;
            if (WDF) {
                f16x8 h;
#pragma unroll
                for (int k = 0; k < 8; ++k) h[k] = (_Float16)dd[k];
                df[((size_t)i * NN + jg) >> 3] = h;
            }
            if (EPI) {
                const float wi = w * s1ci;  // w * sigma^5[i]
                of[u]     = f32x4{v0.x + wi * s0cv[0], v0.y, v0.z + wi * s0cv[1], v0.w};
                of[u + 1] = f32x4{v1.x + wi * s0cv[2], v1.y, v1.z + wi * s0cv[3], v1.w};
                of[u + 2] = f32x4{v2.x + wi * s0cv[4], v2.y, v2.z + wi * s0cv[5], v2.w};
                of[u + 3] = f32x4{v3.x + wi * s0cv[6], v3.y, v3.z + wi * s0cv[7], v3.w};
            }
        }
        float rowp = 0.f;
#pragma unroll
        for (int k = 0; k < 8; ++k) {
            float f1 = sigmoidf_(dd[k] - s1pi * ws0p[k]);
            colacc[k] += s1ci * f1;
            rowp += f1 * s0cv[k];
        }
        // reduce across the 16 col-threads of this row (fixed order, in-wave)
        rowp += __shfl_xor(rowp, 1);
        rowp += __shfl_xor(rowp, 2);
        rowp += __shfl_xor(rowp, 4);
        rowp += __shfl_xor(rowp, 8);
        if (c == 0) rpO[(size_t)ct * NN + i] = rowp;
    }

    // reduce colacc over the 16 row-groups: xor within wave, then LDS over 4 waves
#pragma unroll
    for (int k = 0; k < 8; ++k) {
        colacc[k] += __shfl_xor(colacc[k], 16);
        colacc[k] += __shfl_xor(colacc[k], 32);
    }
    const int wv = t >> 6;
    if ((t & 48) == 0) {  // lanes 0..15 of each wave
#pragma unroll
        for (int k = 0; k < 8; ++k) colred[wv][c * 8 + k] = colacc[k];
    }
    __syncthreads();
    if (t < TILE) {
        float v = colred[0][t] + colred[1][t] + colred[2][t] + colred[3][t];
        cpO[(size_t)rt * NN + j0 + t] = v;
    }
}

// out_s from step-5 partials (16 blocks x 256 threads)
__global__ __launch_bounds__(256) void outs_kernel(
    const float2* __restrict__ bs, const float* __restrict__ rp5,
    const float* __restrict__ cp5, const float* __restrict__ wptr,
    float2* __restrict__ out_s) {
    const int x = blockIdx.x * 256 + threadIdx.x;
    float m0 = 0.f, m1 = 0.f;
#pragma unroll
    for (int s = 0; s < NPART; ++s) {
        m0 += rp5[(size_t)s * NN + x];
        m1 += cp5[(size_t)s * NN + x];
    }
    const float w = wptr[0];
    float2 b = bs[x];
    out_s[x] = make_float2(b.x + w * m0, b.y + w * m1);
}

extern "C" void kernel_launch(void* const* d_in, const int* in_sizes, int n_in,
                              void* d_out, int out_size, void* d_ws,
                              size_t ws_size, hipStream_t stream) {
    const float2* bs = (const float2*)d_in[0];   // (N,2)
    const f32x4* bf = (const f32x4*)d_in[1];     // (N,N,2)
    const float* wptr = (const float*)d_in[2];   // (1,)
    float2* out_s = (float2*)d_out;
    f32x4* out_f = (f32x4*)((float*)d_out + 2 * NN);

    char* ws = (char*)d_ws;
    size_t off = 0;
    auto alloc = [&](size_t bytes) {
        void* p = ws + off;
        off = (off + bytes + 255) & ~(size_t)255;
        return p;
    };
    // 3 rotating partial buffers: each = rowpart[32][NN] + colpart[32][NN]
    const size_t PSZ = (size_t)NPART * NN;  // floats per half
    float* P0 = (float*)alloc(2 * PSZ * 4);
    float* P1 = (float*)alloc(2 * PSZ * 4);
    float* P2 = (float*)alloc(2 * PSZ * 4);
    f16x8* df = (f16x8*)(ws + off);
    const bool use_df = (ws_size >= off + (size_t)NN * NN * 2);

    auto rp = [&](float* P) { return P; };
    auto cp = [&](float* P) { return P + PSZ; };

    const dim3 gP(NBLK), bP(TPB);
    const float* nil = nullptr;

    // P1 (step 1): read bf, write df, partials -> P0 (m^1)
    if (use_df)
        pass_kernel<1, 0, 1, 0><<<gP, bP, 0, stream>>>(
            bs, bf, df, nullptr, nil, nil, nil, nil, rp(P0), cp(P0), wptr);
    else
        pass_kernel<1, 0, 0, 0><<<gP, bP, 0, stream>>>(
            bs, bf, df, nullptr, nil, nil, nil, nil, rp(P0), cp(P0), wptr);

    if (use_df) {
        // step 2: cur=sigma^2 (P0), prev=sigma^1 (bs); read df; -> P1 (m^2)
        pass_kernel<2, 1, 0, 0><<<gP, bP, 0, stream>>>(
            bs, bf, df, nullptr, rp(P0), cp(P0), nil, nil, rp(P1), cp(P1), wptr);
        // step 3: cur=sigma^3 (P1), prev=sigma^2 (P0); -> P2 (m^3)
        pass_kernel<3, 1, 0, 0><<<gP, bP, 0, stream>>>(
            bs, bf, df, nullptr, rp(P1), cp(P1), rp(P0), cp(P0), rp(P2), cp(P2), wptr);
        // step 4: cur=sigma^4 (P2), prev=sigma^3 (P1); -> P0 (m^4)
        pass_kernel<3, 1, 0, 0><<<gP, bP, 0, stream>>>(
            bs, bf, df, nullptr, rp(P2), cp(P2), rp(P1), cp(P1), rp(P0), cp(P0), wptr);
    } else {
        pass_kernel<2, 0, 0, 0><<<gP, bP, 0, stream>>>(
            bs, bf, df, nullptr, rp(P0), cp(P0), nil, nil, rp(P1), cp(P1), wptr);
        pass_kernel<3, 0, 0, 0><<<gP, bP, 0, stream>>>(
            bs, bf, df, nullptr, rp(P1), cp(P1), rp(P0), cp(P0), rp(P2), cp(P2), wptr);
        pass_kernel<3, 0, 0, 0><<<gP, bP, 0, stream>>>(
            bs, bf, df, nullptr, rp(P2), cp(P2), rp(P1), cp(P1), rp(P0), cp(P0), wptr);
    }
    // step 5: cur=sigma^5 (P0=m^4), prev=sigma^4 (P2=m^3); read bf, out_f epilogue;
    // partials -> P1 (m^5)
    pass_kernel<3, 0, 0, 1><<<gP, bP, 0, stream>>>(
        bs, bf, df, out_f, rp(P0), cp(P0), rp(P2), cp(P2), rp(P1), cp(P1), wptr);
    // out_s from m^5
    outs_kernel<<<NN / 256, 256, 0, stream>>>(bs, rp(P1), cp(P1), wptr, out_s);
}

// Round 10
// 187.676 us; speedup vs baseline: 1.1211x; 1.1211x over previous
//
#include <hip/hip_runtime.h>
#include <hip/hip_fp16.h>

#define NN 4096
constexpr int TPB = 256;
constexpr int NSTRIP = 2;                    // column strips of 2048
constexpr int CPB = 2048;                    // 256 thr x 8 cols
constexpr int RPB = 4;                       // rows per block-tile
constexpr int NROWG = NN / RPB;              // 1024 row groups
constexpr int NRSLOT = NSTRIP * (TPB / 64);  // 8 row-partial slots
constexpr int NBLK = NSTRIP * NROWG;         // 2048 blocks (8/CU, full occupancy)
constexpr unsigned BF_LINES = 1048576u;      // N*N*2 floats / 32 floats-per-128B-line

typedef float    f32x4 __attribute__((ext_vector_type(4)));
typedef _Float16 f16x8 __attribute__((ext_vector_type(8)));

__device__ __forceinline__ float sigmoidf_(float x) {
    return 1.0f / (1.0f + __expf(-x));
}

// MODE: 0 = step1 from bf (sigma^1 inline), write fp16 df
//       1 = step1 from bf, no df write (fallback)
//       2 = mid step from fp16 df (+ bf L3-warm prefetch third pf=0..2)
//       3 = mid step from bf (fallback)
//       4 = step5 from bf + out_f epilogue
template <int MODE>
__global__ __launch_bounds__(TPB) void pass_kernel(
    const float2* __restrict__ bs, const f32x4* __restrict__ bf,
    f16x8* __restrict__ df, f32x4* __restrict__ of,
    const float* __restrict__ s1c, const float* __restrict__ s1p,
    const float* __restrict__ wptr,
    float* __restrict__ rowpart, float* __restrict__ colpart,
    float* __restrict__ s1store, int pf) {
    const int t = threadIdx.x;
    const int bid = blockIdx.x;
    const int strip = bid & (NSTRIP - 1);
    const int rg = bid >> 1;
    const int j0 = strip * CPB + t * 8;
    const int i0 = rg * RPB;
    const float w = wptr[0];

    // L3-warm prefetch of base_f during L3-fed step passes (uses idle HBM BW).
    // One dword per 128B line refreshes the line's recency so out_f's
    // write-allocate during pass5 evicts dead lines instead of unread bf.
    float pfv = 0.0f;
    if (MODE == 2) {
        const unsigned b0 = (BF_LINES * (unsigned)pf) / 3u;
        const unsigned b1 = (BF_LINES * (unsigned)(pf + 1)) / 3u;
        const unsigned line = b0 + (unsigned)bid * TPB + (unsigned)t;
        if (line < b1) pfv = reinterpret_cast<const float*>(bf)[(size_t)line * 32];
    }

    float s0cv[8], ws0p[8];
#pragma unroll
    for (int k = 0; k < 8; ++k) {
        if (MODE <= 1) {
            float2 v = bs[j0 + k];
            s0cv[k] = 1.0f - sigmoidf_(v.y - v.x);
            ws0p[k] = 0.0f;
        } else {
            s0cv[k] = 1.0f - s1c[j0 + k];
            ws0p[k] = w * (1.0f - s1p[j0 + k]);
        }
    }
    if (MODE <= 1) {  // 16 blocks persist sigma^1 for step 2's prev
        if (bid < NN / TPB) {
            int x = bid * TPB + t;
            float2 v = bs[x];
            s1store[x] = sigmoidf_(v.y - v.x);
        }
    }
    float colacc[8] = {0.f, 0.f, 0.f, 0.f, 0.f, 0.f, 0.f, 0.f};

#pragma unroll
    for (int r = 0; r < RPB; ++r) {
        const int i = i0 + r;
        float s1ci, s1pi;
        if (MODE <= 1) {
            float2 v = bs[i];
            s1ci = sigmoidf_(v.y - v.x);
            s1pi = 0.0f;
        } else {
            s1ci = s1c[i];
            s1pi = s1p[i];
        }
        float dd[8];
        if (MODE == 2) {
            f16x8 h = df[((size_t)i * NN + j0) >> 3];
#pragma unroll
            for (int k = 0; k < 8; ++k) dd[k] = (float)h[k];
        } else {
            const size_t u = ((size_t)i * NN + j0) >> 1;  // f32x4 index
            f32x4 v0 = bf[u], v1 = bf[u + 1], v2 = bf[u + 2], v3 = bf[u + 3];
            dd[0] = v0.y - v0.x; dd[1] = v0.w - v0.z;
            dd[2] = v1.y - v1.x; dd[3] = v1.w - v1.z;
            dd[4] = v2.y - v2.x; dd[5] = v2.w - v2.z;
            dd[6] = v3.y - v3.x; dd[7] = v3.w - v3.z;
            if (MODE == 0) {
                f16x8 h;
#pragma unroll
                for (int k = 0; k < 8; ++k) h[k] = (_Float16)dd[k];
                df[((size_t)i * NN + j0) >> 3] = h;
            }
            if (MODE == 4) {
                const float wi = w * s1ci;  // w * sigma^5[i]
                of[u]     = f32x4{v0.x + wi * s0cv[0], v0.y, v0.z + wi * s0cv[1], v0.w};
                of[u + 1] = f32x4{v1.x + wi * s0cv[2], v1.y, v1.z + wi * s0cv[3], v1.w};
                of[u + 2] = f32x4{v2.x + wi * s0cv[4], v2.y, v2.z + wi * s0cv[5], v2.w};
                of[u + 3] = f32x4{v3.x + wi * s0cv[6], v3.y, v3.z + wi * s0cv[7], v3.w};
            }
        }
        float rowp = 0.f;
#pragma unroll
        for (int k = 0; k < 8; ++k) {
            float f1 = sigmoidf_(dd[k] - s1pi * ws0p[k]);
            colacc[k] += s1ci * f1;
            rowp += f1 * s0cv[k];
        }
#pragma unroll
        for (int off = 32; off > 0; off >>= 1) rowp += __shfl_down(rowp, off);
        if ((t & 63) == 0)
            rowpart[(size_t)(strip * (TPB / 64) + (t >> 6)) * NN + i] = rowp;
    }
    float* cp = colpart + (size_t)rg * NN + j0;
    *reinterpret_cast<f32x4*>(cp) = f32x4{colacc[0], colacc[1], colacc[2], colacc[3]};
    *reinterpret_cast<f32x4*>(cp + 4) = f32x4{colacc[4], colacc[5], colacc[6], colacc[7]};

    if (MODE == 2) asm volatile("" : : "v"(pfv));  // keep prefetch live (no DCE)
}

// 64 blocks x 1024 threads: 16 slices x 64 columns. Slice sl sums colpart
// groups [sl*64, sl*64+64); slices 0..7 also pick up one rowpart slot.
__global__ __launch_bounds__(1024) void update_kernel(
    const float* __restrict__ rowpart, const float* __restrict__ colpart,
    const float2* __restrict__ bs, const float* __restrict__ wptr,
    float* __restrict__ s1next, float2* __restrict__ out_s, int writeOut) {
    __shared__ float red0[16][64];
    __shared__ float red1[16][64];
    const int col = threadIdx.x & 63;
    const int sl = threadIdx.x >> 6;  // 0..15
    const int x = blockIdx.x * 64 + col;

    float acc1 = 0.f;
    const int g0 = sl * (NROWG / 16);
#pragma unroll 8
    for (int g = g0; g < g0 + NROWG / 16; ++g) acc1 += colpart[(size_t)g * NN + x];
    red1[sl][col] = acc1;
    red0[sl][col] = (sl < NRSLOT) ? rowpart[(size_t)sl * NN + x] : 0.f;
    __syncthreads();
    if (sl == 0) {
        float m0 = 0.f, m1 = 0.f;
#pragma unroll
        for (int s = 0; s < 16; ++s) {
            m0 += red0[s][col];
            m1 += red1[s][col];
        }
        float w = wptr[0];
        float2 b = bs[x];
        float c0 = b.x + w * m0;
        float c1 = b.y + w * m1;
        if (writeOut) out_s[x] = make_float2(c0, c1);
        else s1next[x] = sigmoidf_(c1 - c0);
    }
}

extern "C" void kernel_launch(void* const* d_in, const int* in_sizes, int n_in,
                              void* d_out, int out_size, void* d_ws,
                              size_t ws_size, hipStream_t stream) {
    const float2* bs = (const float2*)d_in[0];   // (N,2)
    const f32x4* bf = (const f32x4*)d_in[1];     // (N,N,2)
    const float* wptr = (const float*)d_in[2];   // (1,)
    float2* out_s = (float2*)d_out;
    f32x4* out_f = (f32x4*)((float*)d_out + 2 * NN);

    char* ws = (char*)d_ws;
    size_t off = 0;
    auto alloc = [&](size_t bytes) {
        void* p = ws + off;
        off = (off + bytes + 255) & ~(size_t)255;
        return p;
    };
    float* sa = (float*)alloc((size_t)NN * 4);
    float* sb = (float*)alloc((size_t)NN * 4);
    float* sc = (float*)alloc((size_t)NN * 4);
    float* rowpart = (float*)alloc((size_t)NRSLOT * NN * 4);
    float* colpart = (float*)alloc((size_t)NROWG * NN * 4);
    f16x8* df = (f16x8*)(ws + off);
    const bool use_df = (ws_size >= off + (size_t)NN * NN * 2);

    const dim3 gP(NBLK), bP(TPB);
    const dim3 gU(NN / 64), bU(1024);

    // step 1: sigma^1 inline (sa), df written; update -> sb = sigma^2
    if (use_df)
        pass_kernel<0><<<gP, bP, 0, stream>>>(bs, bf, df, nullptr, nullptr,
                                              nullptr, wptr, rowpart, colpart, sa, -1);
    else
        pass_kernel<1><<<gP, bP, 0, stream>>>(bs, bf, df, nullptr, nullptr,
                                              nullptr, wptr, rowpart, colpart, sa, -1);
    update_kernel<<<gU, bU, 0, stream>>>(rowpart, colpart, bs, wptr, sb, nullptr, 0);

    if (use_df) {
        // step 2: cur=sigma^2, prev=sigma^1 -> sc = sigma^3 (prefetch bf third 0)
        pass_kernel<2><<<gP, bP, 0, stream>>>(bs, bf, df, nullptr, sb, sa, wptr,
                                              rowpart, colpart, nullptr, 0);
        update_kernel<<<gU, bU, 0, stream>>>(rowpart, colpart, bs, wptr, sc, nullptr, 0);
        // step 3: cur=sigma^3, prev=sigma^2 -> sa = sigma^4 (prefetch third 1)
        pass_kernel<2><<<gP, bP, 0, stream>>>(bs, bf, df, nullptr, sc, sb, wptr,
                                              rowpart, colpart, nullptr, 1);
        update_kernel<<<gU, bU, 0, stream>>>(rowpart, colpart, bs, wptr, sa, nullptr, 0);
        // step 4: cur=sigma^4, prev=sigma^3 -> sb = sigma^5 (prefetch third 2)
        pass_kernel<2><<<gP, bP, 0, stream>>>(bs, bf, df, nullptr, sa, sc, wptr,
                                              rowpart, colpart, nullptr, 2);
        update_kernel<<<gU, bU, 0, stream>>>(rowpart, colpart, bs, wptr, sb, nullptr, 0);
    } else {
        pass_kernel<3><<<gP, bP, 0, stream>>>(bs, bf, df, nullptr, sb, sa, wptr,
                                              rowpart, colpart, nullptr, -1);
        update_kernel<<<gU, bU, 0, stream>>>(rowpart, colpart, bs, wptr, sc, nullptr, 0);
        pass_kernel<3><<<gP, bP, 0, stream>>>(bs, bf, df, nullptr, sc, sb, wptr,
                                              rowpart, colpart, nullptr, -1);
        update_kernel<<<gU, bU, 0, stream>>>(rowpart, colpart, bs, wptr, sa, nullptr, 0);
        pass_kernel<3><<<gP, bP, 0, stream>>>(bs, bf, df, nullptr, sa, sc, wptr,
                                              rowpart, colpart, nullptr, -1);
        update_kernel<<<gU, bU, 0, stream>>>(rowpart, colpart, bs, wptr, sb, nullptr, 0);
    }
    // step 5: cur=sigma^5 (sb), prev=sigma^4 (sa); fused out_f epilogue
    pass_kernel<4><<<gP, bP, 0, stream>>>(bs, bf, df, out_f, sb, sa, wptr,
                                          rowpart, colpart, nullptr, -1);
    update_kernel<<<gU, bU, 0, stream>>>(rowpart, colpart, bs, wptr, nullptr, out_s, 1);
}

// Round 11
// 149.914 us; speedup vs baseline: 1.4035x; 1.2519x over previous
//
#include <hip/hip_runtime.h>

#define NN 4096
constexpr int TPB = 256;
constexpr int NSTRIP = 2;                    // column strips of 2048
constexpr int CPB = 2048;                    // 256 thr x 8 cols
constexpr int RPB = 8;                       // rows per block-tile
constexpr int NROWG = NN / RPB;              // 512 row groups
constexpr int NRSLOT = NSTRIP * (TPB / 64);  // 8 row-partial slots
constexpr int NBLK = NSTRIP * NROWG;         // 1024 blocks (4/CU co-resident)

typedef float f32x4 __attribute__((ext_vector_type(4)));
typedef float f32x2 __attribute__((ext_vector_type(2)));

__device__ __forceinline__ float sigmoidf_(float x) {
    return 1.0f / (1.0f + __expf(-x));
}

// MODE: 0 = step1 from bf (sigma^1 inline), write fp8 df
//       1 = step1 from bf, no df write (fallback)
//       2 = mid step from fp8 df            3 = mid step from bf (fallback)
//       4 = step5 from bf + out_f epilogue
template <int MODE>
__global__ __launch_bounds__(TPB) void pass_kernel(
    const float2* __restrict__ bs, const f32x4* __restrict__ bf,
    uint2* __restrict__ df, f32x4* __restrict__ of,
    const float* __restrict__ s1c, const float* __restrict__ s1p,
    const float* __restrict__ wptr,
    float* __restrict__ rowpart, float* __restrict__ colpart,
    float* __restrict__ s1store) {
    const int t = threadIdx.x;
    const int bid = blockIdx.x;
    const int strip = bid & (NSTRIP - 1);
    const int rg = bid >> 1;
    const int j0 = strip * CPB + t * 8;
    const int i0 = rg * RPB;
    const float w = wptr[0];

    float s0cv[8], ws0p[8];
#pragma unroll
    for (int k = 0; k < 8; ++k) {
        if (MODE <= 1) {
            float2 v = bs[j0 + k];
            s0cv[k] = 1.0f - sigmoidf_(v.y - v.x);
            ws0p[k] = 0.0f;
        } else {
            s0cv[k] = 1.0f - s1c[j0 + k];
            ws0p[k] = w * (1.0f - s1p[j0 + k]);
        }
    }
    if (MODE <= 1) {  // 16 blocks persist sigma^1 for step 2's prev
        if (bid < NN / TPB) {
            int x = bid * TPB + t;
            float2 v = bs[x];
            s1store[x] = sigmoidf_(v.y - v.x);
        }
    }
    float colacc[8] = {0.f, 0.f, 0.f, 0.f, 0.f, 0.f, 0.f, 0.f};

#pragma unroll 2
    for (int r = 0; r < RPB; ++r) {
        const int i = i0 + r;
        float s1ci, s1pi;
        if (MODE <= 1) {
            float2 v = bs[i];
            s1ci = sigmoidf_(v.y - v.x);
            s1pi = 0.0f;
        } else {
            s1ci = s1c[i];
            s1pi = s1p[i];
        }
        float dd[8];
        if (MODE == 2) {
            uint2 hp = df[((size_t)i * NN + j0) >> 3];
            f32x2 p0 = __builtin_amdgcn_cvt_pk_f32_fp8(hp.x, false);
            f32x2 p1 = __builtin_amdgcn_cvt_pk_f32_fp8(hp.x, true);
            f32x2 p2 = __builtin_amdgcn_cvt_pk_f32_fp8(hp.y, false);
            f32x2 p3 = __builtin_amdgcn_cvt_pk_f32_fp8(hp.y, true);
            dd[0] = p0.x; dd[1] = p0.y; dd[2] = p1.x; dd[3] = p1.y;
            dd[4] = p2.x; dd[5] = p2.y; dd[6] = p3.x; dd[7] = p3.y;
        } else {
            const size_t u = ((size_t)i * NN + j0) >> 1;  // f32x4 index
            f32x4 v0 = bf[u], v1 = bf[u + 1], v2 = bf[u + 2], v3 = bf[u + 3];
            dd[0] = v0.y - v0.x; dd[1] = v0.w - v0.z;
            dd[2] = v1.y - v1.x; dd[3] = v1.w - v1.z;
            dd[4] = v2.y - v2.x; dd[5] = v2.w - v2.z;
            dd[6] = v3.y - v3.x; dd[7] = v3.w - v3.z;
            if (MODE == 0) {
                uint2 hp;
                hp.x = (unsigned)__builtin_amdgcn_cvt_pk_fp8_f32(dd[0], dd[1], 0, false);
                hp.x = (unsigned)__builtin_amdgcn_cvt_pk_fp8_f32(dd[2], dd[3], (int)hp.x, true);
                hp.y = (unsigned)__builtin_amdgcn_cvt_pk_fp8_f32(dd[4], dd[5], 0, false);
                hp.y = (unsigned)__builtin_amdgcn_cvt_pk_fp8_f32(dd[6], dd[7], (int)hp.y, true);
                df[((size_t)i * NN + j0) >> 3] = hp;
            }
            if (MODE == 4) {
                const float wi = w * s1ci;  // w * sigma^5[i]
                of[u]     = f32x4{v0.x + wi * s0cv[0], v0.y, v0.z + wi * s0cv[1], v0.w};
                of[u + 1] = f32x4{v1.x + wi * s0cv[2], v1.y, v1.z + wi * s0cv[3], v1.w};
                of[u + 2] = f32x4{v2.x + wi * s0cv[4], v2.y, v2.z + wi * s0cv[5], v2.w};
                of[u + 3] = f32x4{v3.x + wi * s0cv[6], v3.y, v3.z + wi * s0cv[7], v3.w};
            }
        }
        float rowp = 0.f;
#pragma unroll
        for (int k = 0; k < 8; ++k) {
            float f1 = sigmoidf_(dd[k] - s1pi * ws0p[k]);
            colacc[k] += s1ci * f1;
            rowp += f1 * s0cv[k];
        }
#pragma unroll
        for (int off = 32; off > 0; off >>= 1) rowp += __shfl_down(rowp, off);
        if ((t & 63) == 0)
            rowpart[(size_t)(strip * (TPB / 64) + (t >> 6)) * NN + i] = rowp;
    }
    float* cp = colpart + (size_t)rg * NN + j0;
    *reinterpret_cast<f32x4*>(cp) = f32x4{colacc[0], colacc[1], colacc[2], colacc[3]};
    *reinterpret_cast<f32x4*>(cp + 4) = f32x4{colacc[4], colacc[5], colacc[6], colacc[7]};
}

// 64 blocks x 1024 threads: 16 slices x 64 columns. Slice sl sums colpart
// groups [sl*32, sl*32+32); slices 0..7 also pick up one rowpart slot.
__global__ __launch_bounds__(1024) void update_kernel(
    const float* __restrict__ rowpart, const float* __restrict__ colpart,
    const float2* __restrict__ bs, const float* __restrict__ wptr,
    float* __restrict__ s1next, float2* __restrict__ out_s, int writeOut) {
    __shared__ float red0[16][64];
    __shared__ float red1[16][64];
    const int col = threadIdx.x & 63;
    const int sl = threadIdx.x >> 6;  // 0..15
    const int x = blockIdx.x * 64 + col;

    float acc1 = 0.f;
    const int g0 = sl * (NROWG / 16);
#pragma unroll 8
    for (int g = g0; g < g0 + NROWG / 16; ++g) acc1 += colpart[(size_t)g * NN + x];
    red1[sl][col] = acc1;
    red0[sl][col] = (sl < NRSLOT) ? rowpart[(size_t)sl * NN + x] : 0.f;
    __syncthreads();
    if (sl == 0) {
        float m0 = 0.f, m1 = 0.f;
#pragma unroll
        for (int s = 0; s < 16; ++s) {
            m0 += red0[s][col];
            m1 += red1[s][col];
        }
        float w = wptr[0];
        float2 b = bs[x];
        float c0 = b.x + w * m0;
        float c1 = b.y + w * m1;
        if (writeOut) out_s[x] = make_float2(c0, c1);
        else s1next[x] = sigmoidf_(c1 - c0);
    }
}

extern "C" void kernel_launch(void* const* d_in, const int* in_sizes, int n_in,
                              void* d_out, int out_size, void* d_ws,
                              size_t ws_size, hipStream_t stream) {
    const float2* bs = (const float2*)d_in[0];   // (N,2)
    const f32x4* bf = (const f32x4*)d_in[1];     // (N,N,2)
    const float* wptr = (const float*)d_in[2];   // (1,)
    float2* out_s = (float2*)d_out;
    f32x4* out_f = (f32x4*)((float*)d_out + 2 * NN);

    char* ws = (char*)d_ws;
    size_t off = 0;
    auto alloc = [&](size_t bytes) {
        void* p = ws + off;
        off = (off + bytes + 255) & ~(size_t)255;
        return p;
    };
    float* sa = (float*)alloc((size_t)NN * 4);
    float* sb = (float*)alloc((size_t)NN * 4);
    float* sc = (float*)alloc((size_t)NN * 4);
    float* rowpart = (float*)alloc((size_t)NRSLOT * NN * 4);
    float* colpart = (float*)alloc((size_t)NROWG * NN * 4);
    uint2* df = (uint2*)(ws + off);
    const bool use_df = (ws_size >= off + (size_t)NN * NN);  // 16.8 MB fp8

    const dim3 gP(NBLK), bP(TPB);
    const dim3 gU(NN / 64), bU(1024);

    // step 1: sigma^1 inline (sa), df written; update -> sb = sigma^2
    if (use_df)
        pass_kernel<0><<<gP, bP, 0, stream>>>(bs, bf, df, nullptr, nullptr,
                                              nullptr, wptr, rowpart, colpart, sa);
    else
        pass_kernel<1><<<gP, bP, 0, stream>>>(bs, bf, df, nullptr, nullptr,
                                              nullptr, wptr, rowpart, colpart, sa);
    update_kernel<<<gU, bU, 0, stream>>>(rowpart, colpart, bs, wptr, sb, nullptr, 0);

    if (use_df) {
        // step 2: cur=sigma^2, prev=sigma^1 -> sc = sigma^3
        pass_kernel<2><<<gP, bP, 0, stream>>>(bs, bf, df, nullptr, sb, sa, wptr,
                                              rowpart, colpart, nullptr);
        update_kernel<<<gU, bU, 0, stream>>>(rowpart, colpart, bs, wptr, sc, nullptr, 0);
        // step 3: cur=sigma^3, prev=sigma^2 -> sa = sigma^4
        pass_kernel<2><<<gP, bP, 0, stream>>>(bs, bf, df, nullptr, sc, sb, wptr,
                                              rowpart, colpart, nullptr);
        update_kernel<<<gU, bU, 0, stream>>>(rowpart, colpart, bs, wptr, sa, nullptr, 0);
        // step 4: cur=sigma^4, prev=sigma^3 -> sb = sigma^5
        pass_kernel<2><<<gP, bP, 0, stream>>>(bs, bf, df, nullptr, sa, sc, wptr,
                                              rowpart, colpart, nullptr);
        update_kernel<<<gU, bU, 0, stream>>>(rowpart, colpart, bs, wptr, sb, nullptr, 0);
    } else {
        pass_kernel<3><<<gP, bP, 0, stream>>>(bs, bf, df, nullptr, sb, sa, wptr,
                                              rowpart, colpart, nullptr);
        update_kernel<<<gU, bU, 0, stream>>>(rowpart, colpart, bs, wptr, sc, nullptr, 0);
        pass_kernel<3><<<gP, bP, 0, stream>>>(bs, bf, df, nullptr, sc, sb, wptr,
                                              rowpart, colpart, nullptr);
        update_kernel<<<gU, bU, 0, stream>>>(rowpart, colpart, bs, wptr, sa, nullptr, 0);
        pass_kernel<3><<<gP, bP, 0, stream>>>(bs, bf, df, nullptr, sa, sc, wptr,
                                              rowpart, colpart, nullptr);
        update_kernel<<<gU, bU, 0, stream>>>(rowpart, colpart, bs, wptr, sb, nullptr, 0);
    }
    // step 5: cur=sigma^5 (sb), prev=sigma^4 (sa); fused out_f epilogue
    pass_kernel<4><<<gP, bP, 0, stream>>>(bs, bf, df, out_f, sb, sa, wptr,
                                          rowpart, colpart, nullptr);
    update_kernel<<<gU, bU, 0, stream>>>(rowpart, colpart, bs, wptr, nullptr, out_s, 1);
}